// Round 1
// baseline (37.337 us; speedup 1.0000x reference)
//
#include <hip/hip_runtime.h>

// MetaSR scale-4: the MLP input has only 16 distinct values (4x4 subpixel
// phases), so precompute 16 pred_w matrices then run a 3x3 conv + shuffle.
//
// Derivation (exact in fp32): iy = y>>2, rel0 = (y&3)*0.25, r_rev = 0.25.

#define HID 256
#define NC9 576     // 64 channels * 9 taps
#define NOUT 1728   // 576*3

// ---------------- Kernel 1: pred_w[16][576][4] (xyz used, w=0) -------------
__global__ __launch_bounds__(256) void k_predw(
    const float* __restrict__ w1, const float* __restrict__ b1,
    const float* __restrict__ w2, const float* __restrict__ b2,
    float* __restrict__ predw)
{
    __shared__ float h[HID];
    const int tid   = threadIdx.x;
    const int s     = blockIdx.x >> 3;   // subpixel 0..15
    const int chunk = blockIdx.x & 7;    // 8 chunks of 216 outputs

    const float rel0 = (float)(s >> 2) * 0.25f;
    const float rel1 = (float)(s & 3) * 0.25f;

    // h = relu(mlp_in @ w1 + b1)
    float pre = w1[tid] * rel0 + w1[256 + tid] * rel1
              + w1[512 + tid] * 0.25f + b1[tid];
    h[tid] = fmaxf(pre, 0.0f);
    __syncthreads();

    if (tid < 216) {
        const int o = chunk * 216 + tid;        // 8*216 = 1728 exactly
        float acc = b2[o];
        const float* w2c = w2 + o;
        #pragma unroll 8
        for (int j = 0; j < HID; ++j)
            acc = fmaf(h[j], w2c[j * NOUT], acc);
        const int c9 = o / 3;
        const int oo = o - c9 * 3;
        predw[(s * NC9 + c9) * 4 + oo] = acc;
    }
    // zero the float4 pad lane (once per sub)
    if (chunk == 0) {
        for (int p = tid; p < NC9; p += 256)
            predw[(s * NC9 + p) * 4 + 3] = 0.0f;
    }
}

// ---------------- Kernel 2: conv 3x3x64 -> 3, per-subpixel weights ---------
__global__ __launch_bounds__(256) void k_conv(
    const float* __restrict__ feat, const float* __restrict__ predw,
    float* __restrict__ out)
{
    const int tid   = threadIdx.x;
    const int s     = blockIdx.x >> 4;   // subpixel 0..15
    const int chunk = blockIdx.x & 15;   // 16 chunks of 256 LR cells
    const int cell  = chunk * 256 + tid; // 0..4095
    const int cy = cell >> 6;
    const int cx = cell & 63;

    int   offs[9];
    float msk[9];
    #pragma unroll
    for (int t = 0; t < 9; ++t) {
        const int ry = cy + t / 3 - 1;
        const int rx = cx + t % 3 - 1;
        const bool ok = ((unsigned)ry < 64u) && ((unsigned)rx < 64u);
        const int cry = ry < 0 ? 0 : (ry > 63 ? 63 : ry);
        const int crx = rx < 0 ? 0 : (rx > 63 ? 63 : rx);
        offs[t] = cry * 64 + crx;
        msk[t]  = ok ? 1.0f : 0.0f;
    }

    const float4* pw = (const float4*)predw + s * NC9;
    float a0 = 0.f, a1 = 0.f, a2 = 0.f;

    #pragma unroll 2
    for (int c = 0; c < 64; ++c) {
        const float*  fb  = feat + (c << 12);
        const float4* pwc = pw + c * 9;
        #pragma unroll
        for (int t = 0; t < 9; ++t) {
            const float  v = fb[offs[t]] * msk[t];
            const float4 w = pwc[t];
            a0 = fmaf(v, w.x, a0);
            a1 = fmaf(v, w.y, a1);
            a2 = fmaf(v, w.z, a2);
        }
    }

    const int y = (cy << 2) + (s >> 2);
    const int x = (cx << 2) + (s & 3);
    const int p = y * 256 + x;
    out[p]           = a0;
    out[p + 65536]   = a1;
    out[p + 131072]  = a2;
}

extern "C" void kernel_launch(void* const* d_in, const int* in_sizes, int n_in,
                              void* d_out, int out_size, void* d_ws, size_t ws_size,
                              hipStream_t stream) {
    const float* feat = (const float*)d_in[0];
    const float* w1   = (const float*)d_in[1];
    const float* b1   = (const float*)d_in[2];
    const float* w2   = (const float*)d_in[3];
    const float* b2   = (const float*)d_in[4];
    float* out   = (float*)d_out;
    float* predw = (float*)d_ws;   // 16*576*4 floats = 147456 B

    hipLaunchKernelGGL(k_predw, dim3(128), dim3(256), 0, stream,
                       w1, b1, w2, b2, predw);
    hipLaunchKernelGGL(k_conv, dim3(256), dim3(256), 0, stream,
                       feat, predw, out);
}